// Round 7
// baseline (886.007 us; speedup 1.0000x reference)
//
#include <hip/hip_runtime.h>

#define BATCH 16
#define QT    2048
#define KTOT  2048
#define DIM   1024
#define NITEMS (BATCH * (QT / 32))   // 1024 work items (b, 32-row q-block)

// fused_prep block partition
#define NB_CONV  16384               // conv_k part: 16384 * 256 * 8 elems
#define NB_TRANS 8192                // trans_v part
#define NB_FILL  256                 // fill-mean part (16 b x 16 d-slices)

typedef __attribute__((ext_vector_type(8))) _Float16 f16x8;
typedef __attribute__((ext_vector_type(4))) _Float16 f16x4;
typedef __attribute__((ext_vector_type(2))) _Float16 f16x2;
typedef __attribute__((ext_vector_type(4))) float    f32x4;
typedef __attribute__((ext_vector_type(2))) float    f32x2;

// DPP cross-lane (VALU pipe) 16-lane allreduce: xor1, xor2, xor7(row_half_mirror),
// xor8(row_ror:8). Verified R6: passes, neutral perf vs shfl.
template <int CTRL>
__device__ __forceinline__ float dpp_perm(float x) {
    int i = __builtin_bit_cast(int, x);
    int r = __builtin_amdgcn_update_dpp(i, i, CTRL, 0xF, 0xF, true);
    return __builtin_bit_cast(float, r);
}
__device__ __forceinline__ float row16_allmax(float x) {
    x = fmaxf(x, dpp_perm<0xB1>(x));
    x = fmaxf(x, dpp_perm<0x4E>(x));
    x = fmaxf(x, dpp_perm<0x141>(x));
    x = fmaxf(x, dpp_perm<0x128>(x));
    return x;
}
__device__ __forceinline__ float row16_allsum(float x) {
    x = x + dpp_perm<0xB1>(x);
    x = x + dpp_perm<0x4E>(x);
    x = x + dpp_perm<0x141>(x);
    x = x + dpp_perm<0x128>(x);
    return x;
}

// ---------------------------------------------------------------------------
// Fused prep: one dispatch, three independent block-partitioned phases.
// R1-R6 accounting: the serial prep dispatches cost ~372us every round vs a
// ~115us combined BW roofline. Fusing lets 24832 blocks overlap the
// latency-bound transpose with the BW-bound convert/fill.
//  blocks [0, NB_CONV):                 K fp32 -> Kf fp16 (coalesced x8)
//  blocks [NB_CONV, NB_CONV+NB_TRANS):  V -> Vt[b][d][kt] fp16 (LDS transpose)
//  blocks [.., +NB_FILL):               rows q>=qlen: out = column mean of V
//                                       (fp32 V directly -- no Vt dependency,
//                                        coalesced 256B wave reads/writes)
__global__ __launch_bounds__(256) void fused_prep(
    const float* __restrict__ K, const float* __restrict__ V,
    const int* __restrict__ Qlen,
    _Float16* __restrict__ Kf, _Float16* __restrict__ Vt,
    float* __restrict__ out) {

    __shared__ _Float16 tbuf[64][65];     // trans part
    __shared__ float    red[4][64];       // fill part
    __shared__ float    mcol[64];

    const int tid = threadIdx.x;

    if (blockIdx.x < NB_CONV) {
        // ---- conv_k: 8 fp32 -> 8 fp16 per thread, fully coalesced --------
        const size_t idx = ((size_t)blockIdx.x * 256 + tid) * 8;
        f32x4 a0 = *(const f32x4*)(K + idx);
        f32x4 a1 = *(const f32x4*)(K + idx + 4);
        f16x8 h;
#pragma unroll
        for (int j = 0; j < 4; ++j) { h[j] = (_Float16)a0[j]; h[4 + j] = (_Float16)a1[j]; }
        *(f16x8*)(Kf + idx) = h;
        return;
    }

    if (blockIdx.x < NB_CONV + NB_TRANS) {
        // ---- trans_v: 64x64 tile transpose through LDS -------------------
        const int blk = blockIdx.x - NB_CONV;
        const int b   = blk >> 9;
        const int kt0 = ((blk >> 4) & 31) << 6;
        const int d0  = (blk & 15) << 6;
        const int cr  = tid >> 4;
        const int c4  = (tid & 15) << 2;
#pragma unroll
        for (int p = 0; p < 4; ++p) {
            const int r = cr + p * 16;
            f32x4 v = *(const f32x4*)(V + ((size_t)(b * KTOT + kt0 + r)) * DIM + d0 + c4);
#pragma unroll
            for (int j = 0; j < 4; ++j) tbuf[r][c4 + j] = (_Float16)v[j];
        }
        __syncthreads();
#pragma unroll
        for (int p = 0; p < 4; ++p) {
            const int dr = cr + p * 16;
            f16x4 o;
#pragma unroll
            for (int j = 0; j < 4; ++j) o[j] = tbuf[c4 + j][dr];
            *(f16x4*)(Vt + ((size_t)(b * DIM + d0 + dr)) * KTOT + kt0 + c4) = o;
        }
        return;
    }

    // ---- fill-mean (fp32 V, proven fill_mean_f32 pattern) ----------------
    {
        const int blk = blockIdx.x - (NB_CONV + NB_TRANS);
        const int b  = blk >> 4;
        const int d0 = (blk & 15) << 6;
        const int qlen = Qlen[b];
        const int dc = d0 + (tid & 63);
        const int part = tid >> 6;
        float sm = 0.0f;
        for (int kt = part; kt < KTOT; kt += 4)
            sm += V[((size_t)(b * KTOT + kt)) * DIM + dc];
        red[part][tid & 63] = sm;
        __syncthreads();
        if (tid < 64)
            mcol[tid] = (red[0][tid] + red[1][tid] + red[2][tid] + red[3][tid]) * (1.0f / (float)KTOT);
        __syncthreads();
        const float mv = mcol[tid & 63];
        for (int q = qlen + part; q < QT; q += 4)
            out[((size_t)(b * QT + q)) * DIM + dc] = mv;
    }
}

// ---------------------------------------------------------------------------
// Main flash kernel -- BYTE-IDENTICAL to R6 (377us, passed). 512 thr = 8
// waves; wave w owns D-slice [128w,128w+128). Per-XCD queues + stealing.
__global__ __launch_bounds__(512, 2) void attn_main(
    const float* __restrict__ Q, const int* __restrict__ Qlen, const int* __restrict__ Klen,
    const _Float16* __restrict__ Kf, const _Float16* __restrict__ Vt,
    float* __restrict__ out, unsigned* __restrict__ counter) {

    __shared__ float    sred[2][8][32][34];   // pad 34: f32x2 reads 8B-aligned, 2-way banks (free)
    __shared__ _Float16 pbuf[2][32][40];      // row stride 80B -> 16B-aligned frag reads
    __shared__ float    arow[2][32];
    __shared__ float    lrow[32];
    __shared__ unsigned item_s;

    const int tid  = threadIdx.x;
    const int w    = tid >> 6;            // wave 0..7
    const int ln   = tid & 63;
    const int l16  = ln & 15;
    const int quad = ln >> 4;
    const int d0   = w << 7;              // this wave's D-slice base
    const int sr  = tid >> 4;
    const int scg = tid & 15;

    const unsigned bxcd = (unsigned)(blockIdx.x & 7);
    unsigned gx = bxcd;
    int goff = 0;

    for (;;) {
        __syncthreads();
        if (tid == 0) {
            unsigned pick = 0xFFFFFFFFu;
            while (goff < 8) {
                unsigned it = atomicAdd(&counter[gx], 1u);
                if (it < 128u) { pick = gx * 128u + it; break; }
                ++goff;
                gx = (bxcd + (unsigned)goff) & 7u;
            }
            item_s = pick;
        }
        __syncthreads();
        const unsigned item = item_s;
        if (item == 0xFFFFFFFFu) break;
        const int grp  = (int)(item >> 7);
        const int ii   = (int)(item & 127u);
        const int b    = (grp << 1) + (ii >> 6);
        const int qt   = (ii & 63) << 5;
        const int qlen = Qlen[b];
        if (qt >= qlen) continue;
        const int klen = Klen[b];
        const int nkt  = (klen + 31) >> 5;

        f16x8 qh[2][4], ql[2][4];
#pragma unroll
        for (int mi = 0; mi < 2; ++mi)
#pragma unroll
            for (int kc = 0; kc < 4; ++kc) {
                const float* src = Q + ((size_t)(b * QT + qt + mi * 16 + l16)) * DIM
                                     + d0 + kc * 32 + quad * 8;
                f32x4 a0 = *(const f32x4*)src;
                f32x4 a1 = *(const f32x4*)(src + 4);
                f16x8 h, l;
#pragma unroll
                for (int j = 0; j < 4; ++j) {
                    _Float16 h0 = (_Float16)a0[j];
                    h[j] = h0; l[j] = (_Float16)(a0[j] - (float)h0);
                    _Float16 h1 = (_Float16)a1[j];
                    h[4 + j] = h1; l[4 + j] = (_Float16)(a1[j] - (float)h1);
                }
                qh[mi][kc] = h; ql[mi][kc] = l;
            }

        f32x4 o[2][8];
        const f32x4 fzero = {0.0f, 0.0f, 0.0f, 0.0f};
#pragma unroll
        for (int mi = 0; mi < 2; ++mi)
#pragma unroll
            for (int nd = 0; nd < 8; ++nd) o[mi][nd] = fzero;

        float msx = -3.0e38f, lsx = 0.0f;

        f16x8 kf[2][4];
        {
            const _Float16* kb = Kf + ((size_t)(b * KTOT + l16)) * DIM + d0 + quad * 8;
#pragma unroll
            for (int ni = 0; ni < 2; ++ni)
#pragma unroll
                for (int kc = 0; kc < 4; ++kc)
                    kf[ni][kc] = *(const f16x8*)(kb + (size_t)(ni * 16) * DIM + kc * 32);
        }

        f16x8 vf[8];

        for (int t = 0; t <= nkt; ++t) {
            const int cur = t & 1, prv = cur ^ 1;

            if (t < nkt) {
                f32x4 s00 = fzero, s01 = fzero, s10 = fzero, s11 = fzero;
#pragma unroll
                for (int kc = 0; kc < 4; ++kc) {
                    s00 = __builtin_amdgcn_mfma_f32_16x16x32_f16(qh[0][kc], kf[0][kc], s00, 0, 0, 0);
                    s10 = __builtin_amdgcn_mfma_f32_16x16x32_f16(qh[1][kc], kf[0][kc], s10, 0, 0, 0);
                    s00 = __builtin_amdgcn_mfma_f32_16x16x32_f16(ql[0][kc], kf[0][kc], s00, 0, 0, 0);
                    s10 = __builtin_amdgcn_mfma_f32_16x16x32_f16(ql[1][kc], kf[0][kc], s10, 0, 0, 0);
                    s01 = __builtin_amdgcn_mfma_f32_16x16x32_f16(qh[0][kc], kf[1][kc], s01, 0, 0, 0);
                    s11 = __builtin_amdgcn_mfma_f32_16x16x32_f16(qh[1][kc], kf[1][kc], s11, 0, 0, 0);
                    s01 = __builtin_amdgcn_mfma_f32_16x16x32_f16(ql[0][kc], kf[1][kc], s01, 0, 0, 0);
                    s11 = __builtin_amdgcn_mfma_f32_16x16x32_f16(ql[1][kc], kf[1][kc], s11, 0, 0, 0);
                }

                if (t + 1 < nkt) {
                    const int ktn = (t + 1) << 5;
                    const _Float16* kb = Kf + ((size_t)(b * KTOT + ktn + l16)) * DIM
                                            + d0 + quad * 8;
#pragma unroll
                    for (int ni = 0; ni < 2; ++ni)
#pragma unroll
                        for (int kc = 0; kc < 4; ++kc)
                            kf[ni][kc] = *(const f16x8*)(kb + (size_t)(ni * 16) * DIM + kc * 32);
                }

#pragma unroll
                for (int r2 = 0; r2 < 4; ++r2) {
                    sred[cur][w][quad * 4 + r2][l16]           = s00[r2];
                    sred[cur][w][quad * 4 + r2][16 + l16]      = s01[r2];
                    sred[cur][w][16 + quad * 4 + r2][l16]      = s10[r2];
                    sred[cur][w][16 + quad * 4 + r2][16 + l16] = s11[r2];
                }
            }

            if (t > 0) {
                const int kt0p = (t - 1) << 5;
                const int c0 = scg * 2, c1 = c0 + 1;
                float x0 = 0.0f, x1 = 0.0f;
#pragma unroll
                for (int ww = 0; ww < 8; ++ww) {
                    f32x2 xp = *(const f32x2*)&sred[prv][ww][sr][c0];
                    x0 += xp[0]; x1 += xp[1];
                }
                if (kt0p + c0 >= klen) x0 = -3.0e38f;
                if (kt0p + c1 >= klen) x1 = -3.0e38f;
                const float pm = row16_allmax(fmaxf(x0, x1));
                const float mn    = fmaxf(msx, pm);
                const float alpha = __expf(msx - mn);
                const float p0 = __expf(x0 - mn), p1 = __expf(x1 - mn);
                lsx = lsx * alpha + (p0 + p1);
                msx = mn;
                f16x2 pw; pw[0] = (_Float16)p0; pw[1] = (_Float16)p1;
                *(f16x2*)&pbuf[prv][sr][c0] = pw;
                if (scg == 0) arow[prv][sr] = alpha;
            }

            __syncthreads();

            if (t > 0) {
                f32x4 av0 = *(const f32x4*)&arow[prv][quad * 4];
                f32x4 av1 = *(const f32x4*)&arow[prv][16 + quad * 4];
                bool needr = false;
#pragma unroll
                for (int j = 0; j < 4; ++j)
                    needr = needr || (av0[j] != 1.0f) || (av1[j] != 1.0f);
                if (__any(needr)) {
#pragma unroll
                    for (int nd = 0; nd < 8; ++nd) { o[0][nd] *= av0; o[1][nd] *= av1; }
                }

                f16x8 pa0 = *(const f16x8*)&pbuf[prv][l16][quad * 8];
                f16x8 pa1 = *(const f16x8*)&pbuf[prv][16 + l16][quad * 8];
#pragma unroll
                for (int nd = 0; nd < 8; ++nd) {
                    o[0][nd] = __builtin_amdgcn_mfma_f32_16x16x32_f16(pa0, vf[nd], o[0][nd], 0, 0, 0);
                    o[1][nd] = __builtin_amdgcn_mfma_f32_16x16x32_f16(pa1, vf[nd], o[1][nd], 0, 0, 0);
                }
            }

            if (t < nkt) {
                const int kt0v = t << 5;
#pragma unroll
                for (int nd = 0; nd < 8; ++nd)
                    vf[nd] = *(const f16x8*)(Vt + ((size_t)(b * DIM + d0 + nd * 16 + l16)) * KTOT
                                             + kt0v + quad * 8);
            }
        }

        {
            const float lt = row16_allsum(lsx);
            if (scg == 0) lrow[sr] = lt;
        }
        __syncthreads();
        f32x4 li0, li1;
#pragma unroll
        for (int r2 = 0; r2 < 4; ++r2) {
            li0[r2] = 1.0f / lrow[quad * 4 + r2];
            li1[r2] = 1.0f / lrow[16 + quad * 4 + r2];
        }
#pragma unroll
        for (int mi = 0; mi < 2; ++mi)
#pragma unroll
            for (int r2 = 0; r2 < 4; ++r2) {
                const int row = qt + mi * 16 + quad * 4 + r2;
                if (row < qlen) {
                    const float inv = mi ? li1[r2] : li0[r2];
#pragma unroll
                    for (int nd = 0; nd < 8; ++nd)
                        out[((size_t)(b * QT + row)) * DIM + d0 + nd * 16 + l16] =
                            o[mi][nd][r2] * inv;
                }
            }
    }
}

// ---------------------------------------------------------------------------
// Fallback path (only if ws too small)
__global__ __launch_bounds__(256) void fill_mean_f32(const float* __restrict__ V,
                                                     const int* __restrict__ Qlen,
                                                     float* __restrict__ out) {
    const int b  = blockIdx.x >> 4;
    const int d0 = (blockIdx.x & 15) << 6;
    const int qlen = Qlen[b];
    const int tid = threadIdx.x;
    const int dc = d0 + (tid & 63);
    const int part = tid >> 6;
    __shared__ float red[4][64];
    __shared__ float mcol[64];
    float sm = 0.0f;
    for (int kt = part; kt < KTOT; kt += 4)
        sm += V[((size_t)(b * KTOT + kt)) * DIM + dc];
    red[part][tid & 63] = sm;
    __syncthreads();
    if (tid < 64)
        mcol[tid] = (red[0][tid] + red[1][tid] + red[2][tid] + red[3][tid]) * (1.0f / (float)KTOT);
    __syncthreads();
    const float mv = mcol[tid & 63];
    for (int q = qlen + part; q < QT; q += 4)
        out[((size_t)(b * QT + q)) * DIM + dc] = mv;
}

__global__ __launch_bounds__(512) void attn_naive(
    const float* __restrict__ Q, const float* __restrict__ K, const float* __restrict__ V,
    const int* __restrict__ Qlen, const int* __restrict__ Klen, float* __restrict__ out) {
    const int blk  = blockIdx.x;
    const int b    = blk >> 8;
    const int qb   = (blk & 255) << 3;
    const int qlen = Qlen[b];
    if (qb >= qlen) return;
    const int klen = Klen[b];
    const int tid  = threadIdx.x;
    const int wid  = tid >> 6, ln = tid & 63;
    const int q    = qb + wid;
    __shared__ float kbuf[1024], vbuf[1024];
    f32x4 qr[4];
#pragma unroll
    for (int i = 0; i < 4; ++i)
        qr[i] = *(const f32x4*)(Q + ((size_t)(b * QT + q)) * DIM + i * 256 + ln * 4);
    const f32x4 fzero = {0.0f, 0.0f, 0.0f, 0.0f};
    f32x4 acc[4] = {fzero, fzero, fzero, fzero};
    float m = -3.0e38f, l = 0.0f;
    for (int kt = 0; kt < klen; ++kt) {
        __syncthreads();
        if (tid < 256)
            *(f32x4*)&kbuf[tid * 4] = *(const f32x4*)(K + ((size_t)(b * KTOT + kt)) * DIM + tid * 4);
        else
            *(f32x4*)&vbuf[(tid - 256) * 4] =
                *(const f32x4*)(V + ((size_t)(b * KTOT + kt)) * DIM + (tid - 256) * 4);
        __syncthreads();
        float sp = 0.0f;
#pragma unroll
        for (int i = 0; i < 4; ++i) {
            f32x4 kv = *(const f32x4*)&kbuf[i * 256 + ln * 4];
            sp += qr[i][0] * kv[0] + qr[i][1] * kv[1] + qr[i][2] * kv[2] + qr[i][3] * kv[3];
        }
#pragma unroll
        for (int off = 1; off < 64; off <<= 1) sp += __shfl_xor(sp, off, 64);
        const float mn = fmaxf(m, sp);
        const float a  = __expf(m - mn);
        const float p  = __expf(sp - mn);
        l = l * a + p; m = mn;
#pragma unroll
        for (int i = 0; i < 4; ++i) {
            f32x4 vv = *(const f32x4*)&vbuf[i * 256 + ln * 4];
            acc[i] = acc[i] * a + vv * p;
        }
    }
    if (q < qlen) {
        const float inv = 1.0f / l;
#pragma unroll
        for (int i = 0; i < 4; ++i)
            *(f32x4*)(out + ((size_t)(b * QT + q)) * DIM + i * 256 + ln * 4) = acc[i] * inv;
    }
}

// ---------------------------------------------------------------------------
extern "C" void kernel_launch(void* const* d_in, const int* in_sizes, int n_in,
                              void* d_out, int out_size, void* d_ws, size_t ws_size,
                              hipStream_t stream) {
    (void)in_sizes; (void)n_in; (void)out_size;
    const float* Q    = (const float*)d_in[0];
    const float* K    = (const float*)d_in[1];
    const float* V    = (const float*)d_in[2];
    const int*   Qlen = (const int*)d_in[3];
    const int*   Klen = (const int*)d_in[4];
    float*       out  = (float*)d_out;

    const size_t HALF = (size_t)BATCH * KTOT * DIM;          // 33,554,432 elements
    const size_t NEED = HALF * 2 /*Kf*/ * sizeof(_Float16) + 64; // ~128 MB + counters
    if (ws_size >= NEED) {
        _Float16* kf = (_Float16*)d_ws;
        _Float16* vt = kf + HALF;
        unsigned* ctr = (unsigned*)((char*)d_ws + HALF * 2 * sizeof(_Float16));
        hipMemsetAsync(ctr, 0, 8 * sizeof(unsigned), stream);   // 8 per-XCD queues
        fused_prep<<<dim3(NB_CONV + NB_TRANS + NB_FILL), dim3(256), 0, stream>>>(
            K, V, Qlen, kf, vt, out);
        attn_main<<<dim3(256), dim3(512), 0, stream>>>(Q, Qlen, Klen, kf, vt, out, ctr);
    } else {
        fill_mean_f32<<<dim3(BATCH * 16), dim3(256), 0, stream>>>(V, Qlen, out);
        attn_naive<<<dim3(4096), dim3(512), 0, stream>>>(Q, K, V, Qlen, Klen, out);
    }
}

// Round 8
// 742.774 us; speedup vs baseline: 1.1928x; 1.1928x over previous
//
#include <hip/hip_runtime.h>

#define BATCH 16
#define QT    2048
#define KTOT  2048
#define DIM   1024
#define NITEMS (BATCH * (QT / 32))   // 1024 work items (b, 32-row q-block)

typedef __attribute__((ext_vector_type(8))) _Float16 f16x8;
typedef __attribute__((ext_vector_type(4))) _Float16 f16x4;
typedef __attribute__((ext_vector_type(2))) _Float16 f16x2;
typedef __attribute__((ext_vector_type(4))) float    f32x4;
typedef __attribute__((ext_vector_type(2))) float    f32x2;

// DPP cross-lane 16-lane allreduce (verified R6: passes, neutral perf).
template <int CTRL>
__device__ __forceinline__ float dpp_perm(float x) {
    int i = __builtin_bit_cast(int, x);
    int r = __builtin_amdgcn_update_dpp(i, i, CTRL, 0xF, 0xF, true);
    return __builtin_bit_cast(float, r);
}
__device__ __forceinline__ float row16_allmax(float x) {
    x = fmaxf(x, dpp_perm<0xB1>(x));
    x = fmaxf(x, dpp_perm<0x4E>(x));
    x = fmaxf(x, dpp_perm<0x141>(x));
    x = fmaxf(x, dpp_perm<0x128>(x));
    return x;
}
__device__ __forceinline__ float row16_allsum(float x) {
    x = x + dpp_perm<0xB1>(x);
    x = x + dpp_perm<0x4E>(x);
    x = x + dpp_perm<0x141>(x);
    x = x + dpp_perm<0x128>(x);
    return x;
}

// Workgroup barrier WITHOUT the implicit vmcnt(0) drain __syncthreads emits.
// Only LDS ops (cross-wave sred/pbuf/arow hand-off) are drained; global
// loads into private VGPRs (kf/vf prefetch) stay in flight across the
// barrier -- this lets the ~192KB/tile K+V delivery pipeline across tiles.
__device__ __forceinline__ void barrier_lds_only() {
    __builtin_amdgcn_sched_barrier(0);
    asm volatile("s_waitcnt lgkmcnt(0)" ::: "memory");
    __builtin_amdgcn_s_barrier();
    __builtin_amdgcn_sched_barrier(0);
}

// ---------------------------------------------------------------------------
// K fp32 -> fp16 (R6-verified prep; R7 fusion regressed -- reverted)
__global__ __launch_bounds__(256) void conv_k(const float* __restrict__ K,
                                              _Float16* __restrict__ Kf) {
    const size_t idx = ((size_t)blockIdx.x * 256 + threadIdx.x) * 8;
    f32x4 a0 = *(const f32x4*)(K + idx);
    f32x4 a1 = *(const f32x4*)(K + idx + 4);
    f16x8 h;
#pragma unroll
    for (int j = 0; j < 4; ++j) { h[j] = (_Float16)a0[j]; h[4 + j] = (_Float16)a1[j]; }
    *(f16x8*)(Kf + idx) = h;
}

// ---------------------------------------------------------------------------
// V[b][kt][d] fp32 -> Vt[b][d][kt] fp16
__global__ __launch_bounds__(256) void trans_v(const float* __restrict__ V,
                                               _Float16* __restrict__ Vt) {
    const int blk = blockIdx.x;
    const int b   = blk >> 9;
    const int kt0 = ((blk >> 4) & 31) << 6;
    const int d0  = (blk & 15) << 6;
    __shared__ _Float16 tbuf[64][65];
    const int tid = threadIdx.x;
    const int cr  = tid >> 4;
    const int c4  = (tid & 15) << 2;
#pragma unroll
    for (int p = 0; p < 4; ++p) {
        const int r = cr + p * 16;
        f32x4 v = *(const f32x4*)(V + ((size_t)(b * KTOT + kt0 + r)) * DIM + d0 + c4);
#pragma unroll
        for (int j = 0; j < 4; ++j) tbuf[r][c4 + j] = (_Float16)v[j];
    }
    __syncthreads();
#pragma unroll
    for (int p = 0; p < 4; ++p) {
        const int dr = cr + p * 16;
        f16x4 o;
#pragma unroll
        for (int j = 0; j < 4; ++j) o[j] = tbuf[c4 + j][dr];
        *(f16x4*)(Vt + ((size_t)(b * DIM + d0 + dr)) * KTOT + kt0 + c4) = o;
    }
}

// ---------------------------------------------------------------------------
// Rows q >= Q_len: output = column mean of V. 4 threads per (b,d) row.
__global__ __launch_bounds__(256) void fill_mean_vt(const _Float16* __restrict__ Vt,
                                                    const int* __restrict__ Qlen,
                                                    float* __restrict__ out) {
    const int gid  = blockIdx.x * 256 + threadIdx.x;  // 0 .. 65535
    const int row  = gid >> 2;                        // (b,d) row 0..16383
    const int part = gid & 3;
    const int b = row >> 10, d = row & 1023;
    const f16x8* src = (const f16x8*)(Vt + (size_t)row * KTOT) + part * (KTOT / 32);
    float s = 0.0f;
    for (int i = 0; i < KTOT / 32; ++i) {
        f16x8 v = src[i];
#pragma unroll
        for (int j = 0; j < 8; ++j) s += (float)v[j];
    }
    s += __shfl_xor(s, 1, 64);
    s += __shfl_xor(s, 2, 64);
    const float mv = s * (1.0f / (float)KTOT);
    const int qlen = Qlen[b];
    for (int q = qlen + part; q < QT; q += 4)
        out[((size_t)(b * QT + q)) * DIM + d] = mv;
}

// ---------------------------------------------------------------------------
// Main flash kernel. Identical to R6 except the in-loop barrier is
// barrier_lds_only() -- K/V register prefetches now survive the barrier.
__global__ __launch_bounds__(512, 2) void attn_main(
    const float* __restrict__ Q, const int* __restrict__ Qlen, const int* __restrict__ Klen,
    const _Float16* __restrict__ Kf, const _Float16* __restrict__ Vt,
    float* __restrict__ out, unsigned* __restrict__ counter) {

    __shared__ float    sred[2][8][32][34];
    __shared__ _Float16 pbuf[2][32][40];
    __shared__ float    arow[2][32];
    __shared__ float    lrow[32];
    __shared__ unsigned item_s;

    const int tid  = threadIdx.x;
    const int w    = tid >> 6;
    const int ln   = tid & 63;
    const int l16  = ln & 15;
    const int quad = ln >> 4;
    const int d0   = w << 7;
    const int sr  = tid >> 4;
    const int scg = tid & 15;

    const unsigned bxcd = (unsigned)(blockIdx.x & 7);
    unsigned gx = bxcd;
    int goff = 0;

    for (;;) {
        __syncthreads();                  // per-item: full barrier is fine (rare)
        if (tid == 0) {
            unsigned pick = 0xFFFFFFFFu;
            while (goff < 8) {
                unsigned it = atomicAdd(&counter[gx], 1u);
                if (it < 128u) { pick = gx * 128u + it; break; }
                ++goff;
                gx = (bxcd + (unsigned)goff) & 7u;
            }
            item_s = pick;
        }
        __syncthreads();
        const unsigned item = item_s;
        if (item == 0xFFFFFFFFu) break;
        const int grp  = (int)(item >> 7);
        const int ii   = (int)(item & 127u);
        const int b    = (grp << 1) + (ii >> 6);
        const int qt   = (ii & 63) << 5;
        const int qlen = Qlen[b];
        if (qt >= qlen) continue;
        const int klen = Klen[b];
        const int nkt  = (klen + 31) >> 5;

        f16x8 qh[2][4], ql[2][4];
#pragma unroll
        for (int mi = 0; mi < 2; ++mi)
#pragma unroll
            for (int kc = 0; kc < 4; ++kc) {
                const float* src = Q + ((size_t)(b * QT + qt + mi * 16 + l16)) * DIM
                                     + d0 + kc * 32 + quad * 8;
                f32x4 a0 = *(const f32x4*)src;
                f32x4 a1 = *(const f32x4*)(src + 4);
                f16x8 h, l;
#pragma unroll
                for (int j = 0; j < 4; ++j) {
                    _Float16 h0 = (_Float16)a0[j];
                    h[j] = h0; l[j] = (_Float16)(a0[j] - (float)h0);
                    _Float16 h1 = (_Float16)a1[j];
                    h[4 + j] = h1; l[4 + j] = (_Float16)(a1[j] - (float)h1);
                }
                qh[mi][kc] = h; ql[mi][kc] = l;
            }

        f32x4 o[2][8];
        const f32x4 fzero = {0.0f, 0.0f, 0.0f, 0.0f};
#pragma unroll
        for (int mi = 0; mi < 2; ++mi)
#pragma unroll
            for (int nd = 0; nd < 8; ++nd) o[mi][nd] = fzero;

        float msx = -3.0e38f, lsx = 0.0f;

        f16x8 kf[2][4];
        {
            const _Float16* kb = Kf + ((size_t)(b * KTOT + l16)) * DIM + d0 + quad * 8;
#pragma unroll
            for (int ni = 0; ni < 2; ++ni)
#pragma unroll
                for (int kc = 0; kc < 4; ++kc)
                    kf[ni][kc] = *(const f16x8*)(kb + (size_t)(ni * 16) * DIM + kc * 32);
        }

        f16x8 vf[8];

        for (int t = 0; t <= nkt; ++t) {
            const int cur = t & 1, prv = cur ^ 1;

            if (t < nkt) {
                f32x4 s00 = fzero, s01 = fzero, s10 = fzero, s11 = fzero;
#pragma unroll
                for (int kc = 0; kc < 4; ++kc) {
                    s00 = __builtin_amdgcn_mfma_f32_16x16x32_f16(qh[0][kc], kf[0][kc], s00, 0, 0, 0);
                    s10 = __builtin_amdgcn_mfma_f32_16x16x32_f16(qh[1][kc], kf[0][kc], s10, 0, 0, 0);
                    s00 = __builtin_amdgcn_mfma_f32_16x16x32_f16(ql[0][kc], kf[0][kc], s00, 0, 0, 0);
                    s10 = __builtin_amdgcn_mfma_f32_16x16x32_f16(ql[1][kc], kf[0][kc], s10, 0, 0, 0);
                    s01 = __builtin_amdgcn_mfma_f32_16x16x32_f16(qh[0][kc], kf[1][kc], s01, 0, 0, 0);
                    s11 = __builtin_amdgcn_mfma_f32_16x16x32_f16(qh[1][kc], kf[1][kc], s11, 0, 0, 0);
                    s01 = __builtin_amdgcn_mfma_f32_16x16x32_f16(ql[0][kc], kf[1][kc], s01, 0, 0, 0);
                    s11 = __builtin_amdgcn_mfma_f32_16x16x32_f16(ql[1][kc], kf[1][kc], s11, 0, 0, 0);
                }

                if (t + 1 < nkt) {
                    const int ktn = (t + 1) << 5;
                    const _Float16* kb = Kf + ((size_t)(b * KTOT + ktn + l16)) * DIM
                                            + d0 + quad * 8;
#pragma unroll
                    for (int ni = 0; ni < 2; ++ni)
#pragma unroll
                        for (int kc = 0; kc < 4; ++kc)
                            kf[ni][kc] = *(const f16x8*)(kb + (size_t)(ni * 16) * DIM + kc * 32);
                }

#pragma unroll
                for (int r2 = 0; r2 < 4; ++r2) {
                    sred[cur][w][quad * 4 + r2][l16]           = s00[r2];
                    sred[cur][w][quad * 4 + r2][16 + l16]      = s01[r2];
                    sred[cur][w][16 + quad * 4 + r2][l16]      = s10[r2];
                    sred[cur][w][16 + quad * 4 + r2][16 + l16] = s11[r2];
                }
            }

            if (t > 0) {
                const int kt0p = (t - 1) << 5;
                const int c0 = scg * 2, c1 = c0 + 1;
                float x0 = 0.0f, x1 = 0.0f;
#pragma unroll
                for (int ww = 0; ww < 8; ++ww) {
                    f32x2 xp = *(const f32x2*)&sred[prv][ww][sr][c0];
                    x0 += xp[0]; x1 += xp[1];
                }
                if (kt0p + c0 >= klen) x0 = -3.0e38f;
                if (kt0p + c1 >= klen) x1 = -3.0e38f;
                const float pm = row16_allmax(fmaxf(x0, x1));
                const float mn    = fmaxf(msx, pm);
                const float alpha = __expf(msx - mn);
                const float p0 = __expf(x0 - mn), p1 = __expf(x1 - mn);
                lsx = lsx * alpha + (p0 + p1);
                msx = mn;
                f16x2 pw; pw[0] = (_Float16)p0; pw[1] = (_Float16)p1;
                *(f16x2*)&pbuf[prv][sr][c0] = pw;
                if (scg == 0) arow[prv][sr] = alpha;
            }

            barrier_lds_only();            // LDS drain + barrier; vmem stays in flight

            if (t > 0) {
                f32x4 av0 = *(const f32x4*)&arow[prv][quad * 4];
                f32x4 av1 = *(const f32x4*)&arow[prv][16 + quad * 4];
                bool needr = false;
#pragma unroll
                for (int j = 0; j < 4; ++j)
                    needr = needr || (av0[j] != 1.0f) || (av1[j] != 1.0f);
                if (__any(needr)) {
#pragma unroll
                    for (int nd = 0; nd < 8; ++nd) { o[0][nd] *= av0; o[1][nd] *= av1; }
                }

                f16x8 pa0 = *(const f16x8*)&pbuf[prv][l16][quad * 8];
                f16x8 pa1 = *(const f16x8*)&pbuf[prv][16 + l16][quad * 8];
#pragma unroll
                for (int nd = 0; nd < 8; ++nd) {
                    o[0][nd] = __builtin_amdgcn_mfma_f32_16x16x32_f16(pa0, vf[nd], o[0][nd], 0, 0, 0);
                    o[1][nd] = __builtin_amdgcn_mfma_f32_16x16x32_f16(pa1, vf[nd], o[1][nd], 0, 0, 0);
                }
            }

            if (t < nkt) {
                const int kt0v = t << 5;
#pragma unroll
                for (int nd = 0; nd < 8; ++nd)
                    vf[nd] = *(const f16x8*)(Vt + ((size_t)(b * DIM + d0 + nd * 16 + l16)) * KTOT
                                             + kt0v + quad * 8);
            }
        }

        {
            const float lt = row16_allsum(lsx);
            if (scg == 0) lrow[sr] = lt;
        }
        __syncthreads();
        f32x4 li0, li1;
#pragma unroll
        for (int r2 = 0; r2 < 4; ++r2) {
            li0[r2] = 1.0f / lrow[quad * 4 + r2];
            li1[r2] = 1.0f / lrow[16 + quad * 4 + r2];
        }
#pragma unroll
        for (int mi = 0; mi < 2; ++mi)
#pragma unroll
            for (int r2 = 0; r2 < 4; ++r2) {
                const int row = qt + mi * 16 + quad * 4 + r2;
                if (row < qlen) {
                    const float inv = mi ? li1[r2] : li0[r2];
#pragma unroll
                    for (int nd = 0; nd < 8; ++nd)
                        out[((size_t)(b * QT + row)) * DIM + d0 + nd * 16 + l16] =
                            o[mi][nd][r2] * inv;
                }
            }
    }
}

// ---------------------------------------------------------------------------
// Fallback path (only if ws too small)
__global__ __launch_bounds__(256) void fill_mean_f32(const float* __restrict__ V,
                                                     const int* __restrict__ Qlen,
                                                     float* __restrict__ out) {
    const int b  = blockIdx.x >> 4;
    const int d0 = (blockIdx.x & 15) << 6;
    const int qlen = Qlen[b];
    const int tid = threadIdx.x;
    const int dc = d0 + (tid & 63);
    const int part = tid >> 6;
    __shared__ float red[4][64];
    __shared__ float mcol[64];
    float sm = 0.0f;
    for (int kt = part; kt < KTOT; kt += 4)
        sm += V[((size_t)(b * KTOT + kt)) * DIM + dc];
    red[part][tid & 63] = sm;
    __syncthreads();
    if (tid < 64)
        mcol[tid] = (red[0][tid] + red[1][tid] + red[2][tid] + red[3][tid]) * (1.0f / (float)KTOT);
    __syncthreads();
    const float mv = mcol[tid & 63];
    for (int q = qlen + part; q < QT; q += 4)
        out[((size_t)(b * QT + q)) * DIM + dc] = mv;
}

__global__ __launch_bounds__(512) void attn_naive(
    const float* __restrict__ Q, const float* __restrict__ K, const float* __restrict__ V,
    const int* __restrict__ Qlen, const int* __restrict__ Klen, float* __restrict__ out) {
    const int blk  = blockIdx.x;
    const int b    = blk >> 8;
    const int qb   = (blk & 255) << 3;
    const int qlen = Qlen[b];
    if (qb >= qlen) return;
    const int klen = Klen[b];
    const int tid  = threadIdx.x;
    const int wid  = tid >> 6, ln = tid & 63;
    const int q    = qb + wid;
    __shared__ float kbuf[1024], vbuf[1024];
    f32x4 qr[4];
#pragma unroll
    for (int i = 0; i < 4; ++i)
        qr[i] = *(const f32x4*)(Q + ((size_t)(b * QT + q)) * DIM + i * 256 + ln * 4);
    const f32x4 fzero = {0.0f, 0.0f, 0.0f, 0.0f};
    f32x4 acc[4] = {fzero, fzero, fzero, fzero};
    float m = -3.0e38f, l = 0.0f;
    for (int kt = 0; kt < klen; ++kt) {
        __syncthreads();
        if (tid < 256)
            *(f32x4*)&kbuf[tid * 4] = *(const f32x4*)(K + ((size_t)(b * KTOT + kt)) * DIM + tid * 4);
        else
            *(f32x4*)&vbuf[(tid - 256) * 4] =
                *(const f32x4*)(V + ((size_t)(b * KTOT + kt)) * DIM + (tid - 256) * 4);
        __syncthreads();
        float sp = 0.0f;
#pragma unroll
        for (int i = 0; i < 4; ++i) {
            f32x4 kv = *(const f32x4*)&kbuf[i * 256 + ln * 4];
            sp += qr[i][0] * kv[0] + qr[i][1] * kv[1] + qr[i][2] * kv[2] + qr[i][3] * kv[3];
        }
#pragma unroll
        for (int off = 1; off < 64; off <<= 1) sp += __shfl_xor(sp, off, 64);
        const float mn = fmaxf(m, sp);
        const float a  = __expf(m - mn);
        const float p  = __expf(sp - mn);
        l = l * a + p; m = mn;
#pragma unroll
        for (int i = 0; i < 4; ++i) {
            f32x4 vv = *(const f32x4*)&vbuf[i * 256 + ln * 4];
            acc[i] = acc[i] * a + vv * p;
        }
    }
    if (q < qlen) {
        const float inv = 1.0f / l;
#pragma unroll
        for (int i = 0; i < 4; ++i)
            *(f32x4*)(out + ((size_t)(b * QT + q)) * DIM + i * 256 + ln * 4) = acc[i] * inv;
    }
}

// ---------------------------------------------------------------------------
extern "C" void kernel_launch(void* const* d_in, const int* in_sizes, int n_in,
                              void* d_out, int out_size, void* d_ws, size_t ws_size,
                              hipStream_t stream) {
    (void)in_sizes; (void)n_in; (void)out_size;
    const float* Q    = (const float*)d_in[0];
    const float* K    = (const float*)d_in[1];
    const float* V    = (const float*)d_in[2];
    const int*   Qlen = (const int*)d_in[3];
    const int*   Klen = (const int*)d_in[4];
    float*       out  = (float*)d_out;

    const size_t HALF = (size_t)BATCH * KTOT * DIM;          // 33,554,432 elements
    const size_t NEED = HALF * 2 /*Kf*/ * sizeof(_Float16) + 64; // ~128 MB + counters
    if (ws_size >= NEED) {
        _Float16* kf = (_Float16*)d_ws;
        _Float16* vt = kf + HALF;
        unsigned* ctr = (unsigned*)((char*)d_ws + HALF * 2 * sizeof(_Float16));
        hipMemsetAsync(ctr, 0, 8 * sizeof(unsigned), stream);   // 8 per-XCD queues
        conv_k<<<dim3(16384), dim3(256), 0, stream>>>(K, kf);
        trans_v<<<dim3(8192), dim3(256), 0, stream>>>(V, vt);
        fill_mean_vt<<<dim3(256), dim3(256), 0, stream>>>(vt, Qlen, out);
        attn_main<<<dim3(256), dim3(512), 0, stream>>>(Q, Qlen, Klen, kf, vt, out, ctr);
    } else {
        fill_mean_f32<<<dim3(BATCH * 16), dim3(256), 0, stream>>>(V, Qlen, out);
        attn_naive<<<dim3(4096), dim3(512), 0, stream>>>(Q, K, V, Qlen, Klen, out);
    }
}